// Round 7
// baseline (597.841 us; speedup 1.0000x reference)
//
#include <hip/hip_runtime.h>
#include <math.h>

#define THW 65536
#define HW  4096
#define C96 96
#ifndef M_PI
#define M_PI 3.14159265358979323846
#endif

// ---------------- basis init (once per launch; ws is re-poisoned each call) --
__global__ __launch_bounds__(256) void init_basis_k(float* __restrict__ b64,
                                                    float* __restrict__ b64T,
                                                    float* __restrict__ b16) {
  int tid = threadIdx.x;
  for (int i = tid; i < 4096; i += 256) {
    int n = i >> 6, x = i & 63;
    double s = sqrt(2.0 / 64.0) * (n == 0 ? sqrt(0.5) : 1.0);
    float v = (float)(cos((double)n * ((double)x + 0.5) * M_PI / 64.0) * s);
    b64[i] = v;
    b64T[x * 64 + n] = v;
  }
  {
    int n = tid >> 4, x = tid & 15;
    double s = sqrt(2.0 / 16.0) * (n == 0 ? sqrt(0.5) : 1.0);
    b16[tid & 255] = (float)(cos((double)n * ((double)x + 0.5) * M_PI / 16.0) * s);
  }
}

// ---------------- depthwise 3x3x3 conv: lane-per-w, shuffle halo, LDS-free ---
struct R3 { float a, b, c; };  // planes t-1, t, t+1 at one (h,w=lane)

#define LOADR(dst, row) { int rr_ = (row); int o_ = rr_ * 64 + lane; \
    dst.a = pmv[o_]; dst.b = pcv[o_]; dst.c = ppv[o_]; }

#define OUTROW(A, B, Cc, row) { \
    float P0, P1, P2; \
    P0 = w27[0]  * A.a;          P1 = w27[1]  * A.a;          P2 = w27[2]  * A.a; \
    P0 = fmaf(w27[3],  B.a, P0); P1 = fmaf(w27[4],  B.a, P1); P2 = fmaf(w27[5],  B.a, P2); \
    P0 = fmaf(w27[6],  Cc.a, P0); P1 = fmaf(w27[7],  Cc.a, P1); P2 = fmaf(w27[8],  Cc.a, P2); \
    P0 = fmaf(w27[9],  A.b, P0); P1 = fmaf(w27[10], A.b, P1); P2 = fmaf(w27[11], A.b, P2); \
    P0 = fmaf(w27[12], B.b, P0); P1 = fmaf(w27[13], B.b, P1); P2 = fmaf(w27[14], B.b, P2); \
    P0 = fmaf(w27[15], Cc.b, P0); P1 = fmaf(w27[16], Cc.b, P1); P2 = fmaf(w27[17], Cc.b, P2); \
    P0 = fmaf(w27[18], A.c, P0); P1 = fmaf(w27[19], A.c, P1); P2 = fmaf(w27[20], A.c, P2); \
    P0 = fmaf(w27[21], B.c, P0); P1 = fmaf(w27[22], B.c, P1); P2 = fmaf(w27[23], B.c, P2); \
    P0 = fmaf(w27[24], Cc.c, P0); P1 = fmaf(w27[25], Cc.c, P1); P2 = fmaf(w27[26], Cc.c, P2); \
    float lft = __shfl_up(P0, 1);  if (lane == 0)  lft = 0.f; \
    float rgt = __shfl_down(P2, 1); if (lane == 63) rgt = 0.f; \
    yp[(row) * 64] = bv + lft + P1 + rgt; }

__global__ __launch_bounds__(256) void dwconv_k(const float* __restrict__ x,
    const float* __restrict__ wv, const float* __restrict__ bias,
    float* __restrict__ y) {
  int lane = threadIdx.x & 63;
  int wvi  = threadIdx.x >> 6;            // 0..3
  int bc   = blockIdx.x;                  // 0..191
  int t    = blockIdx.y * 4 + wvi;        // 0..15
  int h0   = blockIdx.z * 32;             // 0 or 32
  int c    = bc % C96;

  const float* pcv = x + (size_t)bc * THW + (size_t)t * HW;
  const float* pmv = (t > 0)  ? pcv - HW : pcv;
  const float* ppv = (t < 15) ? pcv + HW : pcv;

  float w27[27];
#pragma unroll
  for (int i = 0; i < 27; ++i) w27[i] = wv[c * 27 + i];
  if (t == 0) {
#pragma unroll
    for (int i = 0; i < 9; ++i) w27[i] = 0.f;
  }
  if (t == 15) {
#pragma unroll
    for (int i = 0; i < 9; ++i) w27[18 + i] = 0.f;
  }
  float bv = bias[c];
  float* yp = y + (size_t)bc * THW + (size_t)t * HW + lane;

  R3 s0, s1, s2, s3, n0, n1;
  if (h0 > 0) { LOADR(s0, h0 - 1) } else { s0.a = s0.b = s0.c = 0.f; }
  LOADR(s1, h0)
  LOADR(s2, h0 + 1)
  LOADR(s3, h0 + 2)
#pragma unroll
  for (int p = 0; p < 14; ++p) {
    int h = h0 + 2 * p;
    LOADR(n0, h + 3)
    LOADR(n1, h + 4)
    OUTROW(s0, s1, s2, h)
    OUTROW(s1, s2, s3, h + 1)
    s0 = s2; s1 = s3; s2 = n0; s3 = n1;
  }
  {
    int h = h0 + 28;
    LOADR(n0, h + 3)
    if (h0 == 0) { LOADR(n1, h + 4) }
    else { n1.a = n1.b = n1.c = 0.f; }
    OUTROW(s0, s1, s2, h)
    OUTROW(s1, s2, s3, h + 1)
    s0 = s2; s1 = s3; s2 = n0; s3 = n1;
  }
  {
    int h = h0 + 30;
    OUTROW(s0, s1, s2, h)
    OUTROW(s1, s2, s3, h + 1)
  }
}
#undef LOADR
#undef OUTROW

// ---------------- fe transpose: [THW][96] -> [96][THW] -----------------------
__global__ __launch_bounds__(256) void feT_k(const float* __restrict__ fe,
                                             float* __restrict__ feT) {
  __shared__ float t[96 * 65];
  int tid = threadIdx.x;
  int tok0 = blockIdx.x * 64;
  const float* p = fe + (size_t)tok0 * 96;
  for (int i = tid; i < 6144; i += 256) {
    int tok = i / 96;
    int ch = i - tok * 96;
    t[ch * 65 + tok] = p[i];
  }
  __syncthreads();
  for (int i = tid; i < 6144; i += 256) {
    int ch = i >> 6, tok = i & 63;
    feT[(size_t)ch * THW + tok0 + tok] = t[ch * 65 + tok];
  }
}

// ---------------- LDS-staged 96xN GEMM, 512 threads, TPT tokens/thread -------
// 8 waves x 12 output channels. TPT=8: 5 LDS b128 per 96 FMA (ratio 1/19 vs
// 1/12 at TPT=4) -> LDS pipe no longer 2x oversubscribed. NO min-waves force:
// acc[24]x4 = 96 VGPR must stay in registers (R4 lesson: forcing 4 blocks/CU
// spilled to scratch, WRITE_SIZE 49K->287K). EPI=2 keeps proven TPT=4 config.
#define FMA4(A, WV) \
  A.x = fmaf(WV, v.x, A.x); A.y = fmaf(WV, v.y, A.y); \
  A.z = fmaf(WV, v.z, A.z); A.w = fmaf(WV, v.w, A.w);

template <int EPI, int TPT>
__global__ __launch_bounds__(512) void gemm96_k(
    const float* __restrict__ In, const float* __restrict__ W,
    const float* __restrict__ bias, float* __restrict__ Out,
    float* __restrict__ Out2, const float* __restrict__ zg,
    const float* __restrict__ lnG, const float* __restrict__ lnB,
    const float* __restrict__ scal_c, const float* __restrict__ scal_a,
    int N, size_t inStride, size_t outStride) {
  constexpr int NT   = TPT / 4;                  // float4 groups per thread
  constexpr int BK   = (TPT == 4) ? 32 : 16;     // k-rows per stage
  constexpr int TOKB = 64 * TPT;                 // tokens per block
  constexpr int WP   = (TPT == 4) ? 104 : 96;    // Wt pitch (reads broadcast)
  __shared__ float Wt[96 * WP];
  __shared__ float buf[BK * TOKB];
  int tid = threadIdx.x;
  int wvi = tid >> 6, ln = tid & 63;   // 8 waves
  for (int i = tid; i < 2304; i += 512) {
    int k4 = i / 96, co = i - k4 * 96;
    float4 w4 = *(const float4*)(W + co * 96 + k4 * 4);
    int k = k4 * 4;
    Wt[(k + 0) * WP + co] = w4.x;
    Wt[(k + 1) * WP + co] = w4.y;
    Wt[(k + 2) * WP + co] = w4.z;
    Wt[(k + 3) * WP + co] = w4.w;
  }
  int n0 = blockIdx.x * TOKB + ln * TPT;
  int co0 = wvi * 12;
  const float* ipb = In + blockIdx.y * inStride + n0;
  const float* zpb = (EPI == 2) ? (zg + blockIdx.y * inStride + n0) : nullptr;

  float4 mu4[NT], rs4[NT];
  if (EPI == 2) {   // per-token LN stats for this lane's tokens
#pragma unroll
    for (int t = 0; t < NT; ++t) {
      float4 sum = make_float4(0.f, 0.f, 0.f, 0.f);
      float4 sq  = make_float4(0.f, 0.f, 0.f, 0.f);
#pragma unroll 8
      for (int ci = 0; ci < 96; ++ci) {
        float4 tv = *(const float4*)(ipb + (size_t)ci * N + 4 * t);
        sum.x += tv.x; sum.y += tv.y; sum.z += tv.z; sum.w += tv.w;
        sq.x = fmaf(tv.x, tv.x, sq.x); sq.y = fmaf(tv.y, tv.y, sq.y);
        sq.z = fmaf(tv.z, tv.z, sq.z); sq.w = fmaf(tv.w, tv.w, sq.w);
      }
      const float r96 = 1.0f / 96.0f;
      mu4[t].x = sum.x * r96; mu4[t].y = sum.y * r96;
      mu4[t].z = sum.z * r96; mu4[t].w = sum.w * r96;
      rs4[t].x = rsqrtf(fmaxf(sq.x * r96 - mu4[t].x * mu4[t].x, 0.f) + 1e-5f);
      rs4[t].y = rsqrtf(fmaxf(sq.y * r96 - mu4[t].y * mu4[t].y, 0.f) + 1e-5f);
      rs4[t].z = rsqrtf(fmaxf(sq.z * r96 - mu4[t].z * mu4[t].z, 0.f) + 1e-5f);
      rs4[t].w = rsqrtf(fmaxf(sq.w * r96 - mu4[t].w * mu4[t].w, 0.f) + 1e-5f);
    }
  }

  float4 acc[12 * NT];
#pragma unroll
  for (int j = 0; j < 12; ++j) {
    float bj = bias[co0 + j];
#pragma unroll
    for (int t = 0; t < NT; ++t)
      acc[j * NT + t] = make_float4(bj, bj, bj, bj);
  }

#pragma unroll 1
  for (int kb = 0; kb < 96 / BK; ++kb) {
#pragma unroll
    for (int i = 0; i < BK / 8; ++i) {      // BK rows by 8 waves
      int r = i * 8 + wvi;
      int k = kb * BK + r;
#pragma unroll
      for (int t = 0; t < NT; ++t) {
        float4 v4 = *(const float4*)(ipb + (size_t)k * N + 4 * t);
        if (EPI == 2) {
          float4 zz = *(const float4*)(zpb + (size_t)k * N + 4 * t);
          float lgk = lnG[k], lbk = lnB[k];
          float gx = zz.x * __builtin_amdgcn_rcpf(1.0f + __expf(-zz.x));
          float gy = zz.y * __builtin_amdgcn_rcpf(1.0f + __expf(-zz.y));
          float gz = zz.z * __builtin_amdgcn_rcpf(1.0f + __expf(-zz.z));
          float gw = zz.w * __builtin_amdgcn_rcpf(1.0f + __expf(-zz.w));
          v4.x = fmaf((v4.x - mu4[t].x) * rs4[t].x, lgk, lbk) * gx;
          v4.y = fmaf((v4.y - mu4[t].y) * rs4[t].y, lgk, lbk) * gy;
          v4.z = fmaf((v4.z - mu4[t].z) * rs4[t].z, lgk, lbk) * gz;
          v4.w = fmaf((v4.w - mu4[t].w) * rs4[t].w, lgk, lbk) * gw;
        }
        *(float4*)&buf[r * TOKB + ln * TPT + 4 * t] = v4;
      }
    }
    __syncthreads();
#pragma unroll 4
    for (int kk = 0; kk < BK; ++kk) {
      int k = kb * BK + kk;
      const float4* wr = (const float4*)&Wt[k * WP + co0];
      float4 w0 = wr[0], w1 = wr[1], w2 = wr[2];
#pragma unroll
      for (int t = 0; t < NT; ++t) {
        float4 v = *(const float4*)&buf[kk * TOKB + ln * TPT + 4 * t];
        FMA4(acc[0 * NT + t], w0.x);  FMA4(acc[1 * NT + t], w0.y);
        FMA4(acc[2 * NT + t], w0.z);  FMA4(acc[3 * NT + t], w0.w);
        FMA4(acc[4 * NT + t], w1.x);  FMA4(acc[5 * NT + t], w1.y);
        FMA4(acc[6 * NT + t], w1.z);  FMA4(acc[7 * NT + t], w1.w);
        FMA4(acc[8 * NT + t], w2.x);  FMA4(acc[9 * NT + t], w2.y);
        FMA4(acc[10 * NT + t], w2.z); FMA4(acc[11 * NT + t], w2.w);
      }
    }
    __syncthreads();
  }

  if (EPI == 1) {
    float cv = scal_c[0], al = scal_a[0];
    float rc = 1.0f / (cv + 1e-8f);
#define TAUMAP(T, AA, BB) { \
    float tau = 0.5f * (T) * (1.0f + erff((T) * 0.70710678118654752f)); \
    float ct = cv * tau; \
    float damp = __expf(-0.5f * al * tau); \
    float sc = __sinf(ct), cc = __cosf(ct); \
    AA = damp * (cc + sc * al * 0.5f * rc); BB = damp * sc * rc; }
#pragma unroll 2
    for (int j = 0; j < 12; ++j)
#pragma unroll
      for (int t = 0; t < NT; ++t) {
        float4 a4, b4;
        TAUMAP(acc[j * NT + t].x, a4.x, b4.x);
        TAUMAP(acc[j * NT + t].y, a4.y, b4.y);
        TAUMAP(acc[j * NT + t].z, a4.z, b4.z);
        TAUMAP(acc[j * NT + t].w, a4.w, b4.w);
        *(float4*)(Out  + (size_t)(co0 + j) * N + n0 + 4 * t) = a4;
        *(float4*)(Out2 + (size_t)(co0 + j) * N + n0 + 4 * t) = b4;
      }
#undef TAUMAP
  } else {
    float* op = Out + blockIdx.y * outStride + n0;
#pragma unroll
    for (int j = 0; j < 12; ++j)
#pragma unroll
      for (int t = 0; t < NT; ++t)
        *(float4*)(op + (size_t)(co0 + j) * N + 4 * t) = acc[j * NT + t];
  }
}

// ---------------- fused W+H (I)DCT: wave-uniform basis via SGPR --------------
__global__ __launch_bounds__(256) void wh_k(const float* __restrict__ in,
    float* __restrict__ out, const float* __restrict__ basis) {
  __shared__ float Xs[64 * 65];
  int tid = threadIdx.x;
  int lane = tid & 63;
  int g0 = __builtin_amdgcn_readfirstlane((tid >> 6) * 16);  // 16-col group
  const float* ip = in + (size_t)blockIdx.x * HW;
  float* op = out + (size_t)blockIdx.x * HW;

  for (int i = tid; i < 1024; i += 256) {   // stage full 64x64 plane
    int h = i >> 4, w0x = (i & 15) * 4;
    float4 v = *(const float4*)(ip + h * 64 + w0x);
    float* d = &Xs[h * 65 + w0x];
    d[0] = v.x; d[1] = v.y; d[2] = v.z; d[3] = v.w;
  }
  __syncthreads();

  float accp[16];
#pragma unroll
  for (int j = 0; j < 16; ++j) accp[j] = 0.f;
  {
    const float* xrow = &Xs[lane * 65];
#pragma unroll 4
    for (int w = 0; w < 64; ++w) {
      float xv = xrow[w];
      const float* bw = basis + w * 64 + g0;   // uniform 64B row chunk
      float4 b0 = *(const float4*)(bw);
      float4 b1 = *(const float4*)(bw + 4);
      float4 b2 = *(const float4*)(bw + 8);
      float4 b3 = *(const float4*)(bw + 12);
      accp[0]  = fmaf(xv, b0.x, accp[0]);  accp[1]  = fmaf(xv, b0.y, accp[1]);
      accp[2]  = fmaf(xv, b0.z, accp[2]);  accp[3]  = fmaf(xv, b0.w, accp[3]);
      accp[4]  = fmaf(xv, b1.x, accp[4]);  accp[5]  = fmaf(xv, b1.y, accp[5]);
      accp[6]  = fmaf(xv, b1.z, accp[6]);  accp[7]  = fmaf(xv, b1.w, accp[7]);
      accp[8]  = fmaf(xv, b2.x, accp[8]);  accp[9]  = fmaf(xv, b2.y, accp[9]);
      accp[10] = fmaf(xv, b2.z, accp[10]); accp[11] = fmaf(xv, b2.w, accp[11]);
      accp[12] = fmaf(xv, b3.x, accp[12]); accp[13] = fmaf(xv, b3.y, accp[13]);
      accp[14] = fmaf(xv, b3.z, accp[14]); accp[15] = fmaf(xv, b3.w, accp[15]);
    }
  }
  __syncthreads();                       // all reads of Xs done
  {                                      // in-place: Xs[h][n] = Y[h][n]
    float* trow = &Xs[lane * 65 + g0];
#pragma unroll
    for (int j = 0; j < 16; ++j) trow[j] = accp[j];
  }
  __syncthreads();

  float acc2[16];
#pragma unroll
  for (int j = 0; j < 16; ++j) acc2[j] = 0.f;
#pragma unroll 4
  for (int h = 0; h < 64; ++h) {
    float tv = Xs[h * 65 + lane];
    const float* bw = basis + h * 64 + g0;     // uniform
    float4 b0 = *(const float4*)(bw);
    float4 b1 = *(const float4*)(bw + 4);
    float4 b2 = *(const float4*)(bw + 8);
    float4 b3 = *(const float4*)(bw + 12);
    acc2[0]  = fmaf(tv, b0.x, acc2[0]);  acc2[1]  = fmaf(tv, b0.y, acc2[1]);
    acc2[2]  = fmaf(tv, b0.z, acc2[2]);  acc2[3]  = fmaf(tv, b0.w, acc2[3]);
    acc2[4]  = fmaf(tv, b1.x, acc2[4]);  acc2[5]  = fmaf(tv, b1.y, acc2[5]);
    acc2[6]  = fmaf(tv, b1.z, acc2[6]);  acc2[7]  = fmaf(tv, b1.w, acc2[7]);
    acc2[8]  = fmaf(tv, b2.x, acc2[8]);  acc2[9]  = fmaf(tv, b2.y, acc2[9]);
    acc2[10] = fmaf(tv, b2.z, acc2[10]); acc2[11] = fmaf(tv, b2.w, acc2[11]);
    acc2[12] = fmaf(tv, b3.x, acc2[12]); acc2[13] = fmaf(tv, b3.y, acc2[13]);
    acc2[14] = fmaf(tv, b3.z, acc2[14]); acc2[15] = fmaf(tv, b3.w, acc2[15]);
  }
#pragma unroll
  for (int j = 0; j < 16; ++j)
    op[(g0 + j) * 64 + lane] = acc2[j];
}

// ---------------- fused T-DCT + spectral multiply + T-IDCT -------------------
__global__ __launch_bounds__(256) void tspec_k(const float* __restrict__ U0,
    const float* __restrict__ V0, const float* __restrict__ A,
    const float* __restrict__ Bc, const float* __restrict__ b16,
    float* __restrict__ out) {
  __shared__ float bs[256];
  int tid = threadIdx.x;
  bs[tid] = b16[tid];
  __syncthreads();
  int hw = blockIdx.x * 256 + tid;
  int c = blockIdx.y, b = blockIdx.z;
  size_t base = ((size_t)(b * C96 + c) * 16) * HW + hw;
  int cbase = c * THW + hw;
  float ua[16], va[16];
  {
    float u[16];
#pragma unroll
    for (int t = 0; t < 16; ++t) u[t] = U0[base + t * HW];
#pragma unroll
    for (int n = 0; n < 16; ++n) {
      float s = 0.0f;
#pragma unroll
      for (int t = 0; t < 16; ++t) s = fmaf(bs[n * 16 + t], u[t], s);
      ua[n] = s;
    }
  }
  {
    float v[16];
#pragma unroll
    for (int t = 0; t < 16; ++t) v[t] = V0[base + t * HW];
#pragma unroll
    for (int n = 0; n < 16; ++n) {
      float s = 0.0f;
#pragma unroll
      for (int t = 0; t < 16; ++t) s = fmaf(bs[n * 16 + t], v[t], s);
      va[n] = s;
    }
  }
  float so[16];
#pragma unroll 4
  for (int n = 0; n < 16; ++n)
    so[n] = A[cbase + n * HW] * ua[n] + Bc[cbase + n * HW] * va[n];
#pragma unroll
  for (int t = 0; t < 16; ++t) {
    float s = 0.0f;
#pragma unroll
    for (int n = 0; n < 16; ++n) s = fmaf(so[n], bs[n * 16 + t], s);
    out[base + t * HW] = s;
  }
}

extern "C" void kernel_launch(void* const* d_in, const int* in_sizes, int n_in,
                              void* d_out, int out_size, void* d_ws, size_t ws_size,
                              hipStream_t stream) {
  const float* x    = (const float*)d_in[0];
  const float* fe   = (const float*)d_in[1];
  const float* dww  = (const float*)d_in[2];
  const float* dwb  = (const float*)d_in[3];
  const float* linW = (const float*)d_in[4];
  const float* linB = (const float*)d_in[5];
  const float* v0W  = (const float*)d_in[6];
  const float* v0B  = (const float*)d_in[7];
  const float* tokW = (const float*)d_in[8];
  const float* tokB = (const float*)d_in[9];
  const float* cS   = (const float*)d_in[10];
  const float* aS   = (const float*)d_in[11];
  const float* lnG  = (const float*)d_in[12];
  const float* lnBp = (const float*)d_in[13];
  const float* outW = (const float*)d_in[14];
  const float* outB = (const float*)d_in[15];
  float* out = (float*)d_out;

  float* w = (float*)d_ws;
  const size_t TEN = (size_t)2 * C96 * THW;
  const size_t BST = (size_t)C96 * THW;
  float* b64    = w;                 // 4096
  float* b64T   = w + 4096;          // 4096
  float* b16    = w + 8192;          // 256
  float* buf_y  = w + 16384;
  float* buf_xg = buf_y + TEN;
  float* buf_z  = buf_xg + TEN;
  float* buf_v0 = buf_z + TEN;
  float* bufA   = buf_v0 + TEN;
  float* bufB   = bufA + BST;
  size_t need = (size_t)(16384 + 4 * TEN + 2 * BST) * sizeof(float);
  if (ws_size < need) return;

  hipLaunchKernelGGL(init_basis_k, dim3(1), dim3(256), 0, stream, b64, b64T, b16);
  hipLaunchKernelGGL(dwconv_k, dim3(192, 4, 2), dim3(256), 0, stream, x, dww, dwb, buf_y);
  hipLaunchKernelGGL((gemm96_k<0, 8>), dim3(128, 2), dim3(512), 0, stream,
                     buf_y, linW, linB, buf_xg, (float*)nullptr, (const float*)nullptr,
                     (const float*)nullptr, (const float*)nullptr,
                     (const float*)nullptr, (const float*)nullptr, THW, BST, BST);
  hipLaunchKernelGGL((gemm96_k<0, 8>), dim3(128, 2), dim3(512), 0, stream,
                     buf_y, linW + 9216, linB + 96, buf_z, (float*)nullptr, (const float*)nullptr,
                     (const float*)nullptr, (const float*)nullptr,
                     (const float*)nullptr, (const float*)nullptr, THW, BST, BST);
  hipLaunchKernelGGL(feT_k, dim3(1024), dim3(256), 0, stream, fe, buf_v0);
  hipLaunchKernelGGL((gemm96_k<1, 8>), dim3(128, 1), dim3(512), 0, stream,
                     buf_v0, tokW, tokB, bufA, bufB, (const float*)nullptr,
                     (const float*)nullptr, (const float*)nullptr,
                     cS, aS, THW, (size_t)0, (size_t)0);
  hipLaunchKernelGGL((gemm96_k<0, 8>), dim3(128, 2), dim3(512), 0, stream,
                     buf_xg, v0W, v0B, buf_v0, (float*)nullptr, (const float*)nullptr,
                     (const float*)nullptr, (const float*)nullptr,
                     (const float*)nullptr, (const float*)nullptr, THW, BST, BST);
  hipLaunchKernelGGL(wh_k, dim3(3072), dim3(256), 0, stream, buf_xg, buf_y, b64T);
  hipLaunchKernelGGL(wh_k, dim3(3072), dim3(256), 0, stream, buf_v0, buf_xg, b64T);
  hipLaunchKernelGGL(tspec_k, dim3(16, 96, 2), dim3(256), 0, stream, buf_y, buf_xg, bufA, bufB, b16, buf_v0);
  hipLaunchKernelGGL(wh_k, dim3(3072), dim3(256), 0, stream, buf_v0, buf_y, b64);
  hipLaunchKernelGGL((gemm96_k<2, 4>), dim3(256, 2), dim3(512), 0, stream,
                     buf_y, outW, outB, out, (float*)nullptr, buf_z,
                     lnG, lnBp, (const float*)nullptr, (const float*)nullptr, THW, BST, BST);
}

// Round 8
// 584.624 us; speedup vs baseline: 1.0226x; 1.0226x over previous
//
#include <hip/hip_runtime.h>
#include <math.h>

#define THW 65536
#define HW  4096
#define C96 96
#ifndef M_PI
#define M_PI 3.14159265358979323846
#endif

// ---------------- basis init (once per launch; ws is re-poisoned each call) --
__global__ __launch_bounds__(256) void init_basis_k(float* __restrict__ b64,
                                                    float* __restrict__ b64T,
                                                    float* __restrict__ b16) {
  int tid = threadIdx.x;
  for (int i = tid; i < 4096; i += 256) {
    int n = i >> 6, x = i & 63;
    double s = sqrt(2.0 / 64.0) * (n == 0 ? sqrt(0.5) : 1.0);
    float v = (float)(cos((double)n * ((double)x + 0.5) * M_PI / 64.0) * s);
    b64[i] = v;
    b64T[x * 64 + n] = v;
  }
  {
    int n = tid >> 4, x = tid & 15;
    double s = sqrt(2.0 / 16.0) * (n == 0 ? sqrt(0.5) : 1.0);
    b16[tid & 255] = (float)(cos((double)n * ((double)x + 0.5) * M_PI / 16.0) * s);
  }
}

// ---------------- depthwise 3x3x3 conv: lane-per-w, shuffle halo, LDS-free ---
struct R3 { float a, b, c; };  // planes t-1, t, t+1 at one (h,w=lane)

#define LOADR(dst, row) { int rr_ = (row); int o_ = rr_ * 64 + lane; \
    dst.a = pmv[o_]; dst.b = pcv[o_]; dst.c = ppv[o_]; }

#define OUTROW(A, B, Cc, row) { \
    float P0, P1, P2; \
    P0 = w27[0]  * A.a;          P1 = w27[1]  * A.a;          P2 = w27[2]  * A.a; \
    P0 = fmaf(w27[3],  B.a, P0); P1 = fmaf(w27[4],  B.a, P1); P2 = fmaf(w27[5],  B.a, P2); \
    P0 = fmaf(w27[6],  Cc.a, P0); P1 = fmaf(w27[7],  Cc.a, P1); P2 = fmaf(w27[8],  Cc.a, P2); \
    P0 = fmaf(w27[9],  A.b, P0); P1 = fmaf(w27[10], A.b, P1); P2 = fmaf(w27[11], A.b, P2); \
    P0 = fmaf(w27[12], B.b, P0); P1 = fmaf(w27[13], B.b, P1); P2 = fmaf(w27[14], B.b, P2); \
    P0 = fmaf(w27[15], Cc.b, P0); P1 = fmaf(w27[16], Cc.b, P1); P2 = fmaf(w27[17], Cc.b, P2); \
    P0 = fmaf(w27[18], A.c, P0); P1 = fmaf(w27[19], A.c, P1); P2 = fmaf(w27[20], A.c, P2); \
    P0 = fmaf(w27[21], B.c, P0); P1 = fmaf(w27[22], B.c, P1); P2 = fmaf(w27[23], B.c, P2); \
    P0 = fmaf(w27[24], Cc.c, P0); P1 = fmaf(w27[25], Cc.c, P1); P2 = fmaf(w27[26], Cc.c, P2); \
    float lft = __shfl_up(P0, 1);  if (lane == 0)  lft = 0.f; \
    float rgt = __shfl_down(P2, 1); if (lane == 63) rgt = 0.f; \
    yp[(row) * 64] = bv + lft + P1 + rgt; }

__global__ __launch_bounds__(256) void dwconv_k(const float* __restrict__ x,
    const float* __restrict__ wv, const float* __restrict__ bias,
    float* __restrict__ y) {
  int lane = threadIdx.x & 63;
  int wvi  = threadIdx.x >> 6;            // 0..3
  int bc   = blockIdx.x;                  // 0..191
  int t    = blockIdx.y * 4 + wvi;        // 0..15
  int h0   = blockIdx.z * 32;             // 0 or 32
  int c    = bc % C96;

  const float* pcv = x + (size_t)bc * THW + (size_t)t * HW;
  const float* pmv = (t > 0)  ? pcv - HW : pcv;
  const float* ppv = (t < 15) ? pcv + HW : pcv;

  float w27[27];
#pragma unroll
  for (int i = 0; i < 27; ++i) w27[i] = wv[c * 27 + i];
  if (t == 0) {
#pragma unroll
    for (int i = 0; i < 9; ++i) w27[i] = 0.f;
  }
  if (t == 15) {
#pragma unroll
    for (int i = 0; i < 9; ++i) w27[18 + i] = 0.f;
  }
  float bv = bias[c];
  float* yp = y + (size_t)bc * THW + (size_t)t * HW + lane;

  R3 s0, s1, s2, s3, n0, n1;
  if (h0 > 0) { LOADR(s0, h0 - 1) } else { s0.a = s0.b = s0.c = 0.f; }
  LOADR(s1, h0)
  LOADR(s2, h0 + 1)
  LOADR(s3, h0 + 2)
#pragma unroll
  for (int p = 0; p < 14; ++p) {
    int h = h0 + 2 * p;
    LOADR(n0, h + 3)
    LOADR(n1, h + 4)
    OUTROW(s0, s1, s2, h)
    OUTROW(s1, s2, s3, h + 1)
    s0 = s2; s1 = s3; s2 = n0; s3 = n1;
  }
  {
    int h = h0 + 28;
    LOADR(n0, h + 3)
    if (h0 == 0) { LOADR(n1, h + 4) }
    else { n1.a = n1.b = n1.c = 0.f; }
    OUTROW(s0, s1, s2, h)
    OUTROW(s1, s2, s3, h + 1)
    s0 = s2; s1 = s3; s2 = n0; s3 = n1;
  }
  {
    int h = h0 + 30;
    OUTROW(s0, s1, s2, h)
    OUTROW(s1, s2, s3, h + 1)
  }
}
#undef LOADR
#undef OUTROW

// ---------------- fe transpose: [THW][96] -> [96][THW] -----------------------
__global__ __launch_bounds__(256) void feT_k(const float* __restrict__ fe,
                                             float* __restrict__ feT) {
  __shared__ float t[96 * 65];
  int tid = threadIdx.x;
  int tok0 = blockIdx.x * 64;
  const float* p = fe + (size_t)tok0 * 96;
  for (int i = tid; i < 6144; i += 256) {
    int tok = i / 96;
    int ch = i - tok * 96;
    t[ch * 65 + tok] = p[i];
  }
  __syncthreads();
  for (int i = tid; i < 6144; i += 256) {
    int ch = i >> 6, tok = i & 63;
    feT[(size_t)ch * THW + tok0 + tok] = t[ch * 65 + tok];
  }
}

// ---------------- LDS-staged 96xN GEMM family, 512 threads (R1-verified) -----
// TPT=4 path, used for EPI1/EPI2. acc[12] = 192 B alloca -> promoted to VGPR.
#define FMA4(A, WV) \
  A.x = fmaf(WV, v.x, A.x); A.y = fmaf(WV, v.y, A.y); \
  A.z = fmaf(WV, v.z, A.z); A.w = fmaf(WV, v.w, A.w);

#define WPAD 104
#define BK32 32

template <int EPI>
__global__ __launch_bounds__(512) void gemm96_k(
    const float* __restrict__ In, const float* __restrict__ W,
    const float* __restrict__ bias, float* __restrict__ Out,
    float* __restrict__ Out2, const float* __restrict__ zg,
    const float* __restrict__ lnG, const float* __restrict__ lnB,
    const float* __restrict__ scal_c, const float* __restrict__ scal_a,
    int N, size_t inStride, size_t outStride) {
  __shared__ float Wt[96 * WPAD];      // [k][co], padded (39 KB)
  __shared__ float buf[BK32 * 256];    // 32 KB
  int tid = threadIdx.x;
  int wvi = tid >> 6, ln = tid & 63;   // 8 waves
  for (int i = tid; i < 2304; i += 512) {
    int k4 = i / 96, co = i - k4 * 96;
    float4 w4 = *(const float4*)(W + co * 96 + k4 * 4);
    int k = k4 * 4;
    Wt[(k + 0) * WPAD + co] = w4.x;
    Wt[(k + 1) * WPAD + co] = w4.y;
    Wt[(k + 2) * WPAD + co] = w4.z;
    Wt[(k + 3) * WPAD + co] = w4.w;
  }
  int n0 = blockIdx.x * 256 + ln * 4;
  int co0 = wvi * 12;
  const float* ipb = In + blockIdx.y * inStride + blockIdx.x * 256 + ln * 4;
  const float* zpb = (EPI == 2) ? (zg + blockIdx.y * inStride + blockIdx.x * 256 + ln * 4)
                                : nullptr;

  float4 mu4, rs4;
  if (EPI == 2) {   // per-token LN stats for this lane's 4 tokens
    float4 sum = make_float4(0.f, 0.f, 0.f, 0.f);
    float4 sq  = make_float4(0.f, 0.f, 0.f, 0.f);
#pragma unroll 8
    for (int ci = 0; ci < 96; ++ci) {
      float4 t = *(const float4*)(ipb + (size_t)ci * N);
      sum.x += t.x; sum.y += t.y; sum.z += t.z; sum.w += t.w;
      sq.x = fmaf(t.x, t.x, sq.x); sq.y = fmaf(t.y, t.y, sq.y);
      sq.z = fmaf(t.z, t.z, sq.z); sq.w = fmaf(t.w, t.w, sq.w);
    }
    const float r96 = 1.0f / 96.0f;
    mu4.x = sum.x * r96; mu4.y = sum.y * r96; mu4.z = sum.z * r96; mu4.w = sum.w * r96;
    rs4.x = rsqrtf(fmaxf(sq.x * r96 - mu4.x * mu4.x, 0.f) + 1e-5f);
    rs4.y = rsqrtf(fmaxf(sq.y * r96 - mu4.y * mu4.y, 0.f) + 1e-5f);
    rs4.z = rsqrtf(fmaxf(sq.z * r96 - mu4.z * mu4.z, 0.f) + 1e-5f);
    rs4.w = rsqrtf(fmaxf(sq.w * r96 - mu4.w * mu4.w, 0.f) + 1e-5f);
  }

  float4 acc[12];
#pragma unroll
  for (int j = 0; j < 12; ++j) {
    float bj = bias[co0 + j];
    acc[j] = make_float4(bj, bj, bj, bj);
  }

#pragma unroll 1
  for (int kb = 0; kb < 3; ++kb) {
#pragma unroll
    for (int i = 0; i < 4; ++i) {           // 32 rows by 8 waves
      int r = i * 8 + wvi;
      int k = kb * BK32 + r;
      float4 v4 = *(const float4*)(ipb + (size_t)k * N);
      if (EPI == 2) {
        float4 zz = *(const float4*)(zpb + (size_t)k * N);
        float lgk = lnG[k], lbk = lnB[k];
        float gx = zz.x * __builtin_amdgcn_rcpf(1.0f + __expf(-zz.x));
        float gy = zz.y * __builtin_amdgcn_rcpf(1.0f + __expf(-zz.y));
        float gz = zz.z * __builtin_amdgcn_rcpf(1.0f + __expf(-zz.z));
        float gw = zz.w * __builtin_amdgcn_rcpf(1.0f + __expf(-zz.w));
        v4.x = fmaf((v4.x - mu4.x) * rs4.x, lgk, lbk) * gx;
        v4.y = fmaf((v4.y - mu4.y) * rs4.y, lgk, lbk) * gy;
        v4.z = fmaf((v4.z - mu4.z) * rs4.z, lgk, lbk) * gz;
        v4.w = fmaf((v4.w - mu4.w) * rs4.w, lgk, lbk) * gw;
      }
      *(float4*)&buf[r * 256 + ln * 4] = v4;
    }
    __syncthreads();
#pragma unroll 8
    for (int kk = 0; kk < BK32; ++kk) {
      int k = kb * BK32 + kk;
      float4 v = *(const float4*)&buf[kk * 256 + ln * 4];
      const float4* wr = (const float4*)&Wt[k * WPAD + co0];
#pragma unroll
      for (int j = 0; j < 3; ++j) {
        float4 wvv = wr[j];
        FMA4(acc[4 * j + 0], wvv.x);
        FMA4(acc[4 * j + 1], wvv.y);
        FMA4(acc[4 * j + 2], wvv.z);
        FMA4(acc[4 * j + 3], wvv.w);
      }
    }
    __syncthreads();
  }

  if (EPI == 1) {
    float cv = scal_c[0], al = scal_a[0];
    float rc = 1.0f / (cv + 1e-8f);
#define TAUMAP(T, AA, BB) { \
    float tau = 0.5f * (T) * (1.0f + erff((T) * 0.70710678118654752f)); \
    float ct = cv * tau; \
    float damp = __expf(-0.5f * al * tau); \
    float sc = __sinf(ct), cc = __cosf(ct); \
    AA = damp * (cc + sc * al * 0.5f * rc); BB = damp * sc * rc; }
#pragma unroll 2
    for (int j = 0; j < 12; ++j) {
      float4 a4, b4;
      TAUMAP(acc[j].x, a4.x, b4.x);
      TAUMAP(acc[j].y, a4.y, b4.y);
      TAUMAP(acc[j].z, a4.z, b4.z);
      TAUMAP(acc[j].w, a4.w, b4.w);
      *(float4*)(Out  + (size_t)(co0 + j) * N + n0) = a4;
      *(float4*)(Out2 + (size_t)(co0 + j) * N + n0) = b4;
    }
#undef TAUMAP
  } else {
    float* op = Out + blockIdx.y * outStride + n0;
#pragma unroll
    for (int j = 0; j < 12; ++j)
      *(float4*)(op + (size_t)(co0 + j) * N) = acc[j];
  }
}

// ---------------- TPT=8 GEMM, plain epilogue, NAMED accumulators -------------
// 24 float4 accumulators as named variables (no alloca -> PromoteAlloca can't
// demote to scratch; R4/R7 spills were the 384B acc array exceeding the
// promote threshold). 5 LDS b128 per 96 FMA vs 4 per 48 at TPT=4.
#define INIT1(p, j) float4 p##j; { float bj_ = bias[co0 + j]; \
    p##j = make_float4(bj_, bj_, bj_, bj_); }
#define INIT12(p) INIT1(p,0) INIT1(p,1) INIT1(p,2) INIT1(p,3) INIT1(p,4) \
    INIT1(p,5) INIT1(p,6) INIT1(p,7) INIT1(p,8) INIT1(p,9) INIT1(p,10) INIT1(p,11)
#define FMAS12(p) \
  FMA4(p##0, w0.x); FMA4(p##1, w0.y); FMA4(p##2,  w0.z); FMA4(p##3,  w0.w); \
  FMA4(p##4, w1.x); FMA4(p##5, w1.y); FMA4(p##6,  w1.z); FMA4(p##7,  w1.w); \
  FMA4(p##8, w2.x); FMA4(p##9, w2.y); FMA4(p##10, w2.z); FMA4(p##11, w2.w);
#define ST1(p, j, off) *(float4*)(op + (size_t)(co0 + j) * N + (off)) = p##j;
#define ST12(p, off) ST1(p,0,off) ST1(p,1,off) ST1(p,2,off) ST1(p,3,off) \
    ST1(p,4,off) ST1(p,5,off) ST1(p,6,off) ST1(p,7,off) ST1(p,8,off) \
    ST1(p,9,off) ST1(p,10,off) ST1(p,11,off)

__global__ __launch_bounds__(512, 2) void gemm96x8_k(
    const float* __restrict__ In, const float* __restrict__ W,
    const float* __restrict__ bias, float* __restrict__ Out,
    int N, size_t inStride, size_t outStride) {
  __shared__ float Wt[96 * 96];        // 36 KB, broadcast reads
  __shared__ float buf[16 * 512];      // 32 KB
  int tid = threadIdx.x;
  int wvi = tid >> 6, ln = tid & 63;   // 8 waves
  for (int i = tid; i < 2304; i += 512) {
    int k4 = i / 96, co = i - k4 * 96;
    float4 w4 = *(const float4*)(W + co * 96 + k4 * 4);
    int k = k4 * 4;
    Wt[(k + 0) * 96 + co] = w4.x;
    Wt[(k + 1) * 96 + co] = w4.y;
    Wt[(k + 2) * 96 + co] = w4.z;
    Wt[(k + 3) * 96 + co] = w4.w;
  }
  int n0 = blockIdx.x * 512 + ln * 8;
  int co0 = wvi * 12;
  const float* ipb = In + blockIdx.y * inStride + n0;

  INIT12(A) INIT12(B)

#pragma unroll 1
  for (int kb = 0; kb < 6; ++kb) {
#pragma unroll
    for (int i = 0; i < 2; ++i) {           // 16 rows by 8 waves
      int r = i * 8 + wvi;
      int k = kb * 16 + r;
      float4 v0 = *(const float4*)(ipb + (size_t)k * N);
      float4 v1 = *(const float4*)(ipb + (size_t)k * N + 4);
      *(float4*)&buf[r * 512 + ln * 8]     = v0;
      *(float4*)&buf[r * 512 + ln * 8 + 4] = v1;
    }
    __syncthreads();
#pragma unroll 4
    for (int kk = 0; kk < 16; ++kk) {
      int k = kb * 16 + kk;
      const float4* wr = (const float4*)&Wt[k * 96 + co0];
      float4 w0 = wr[0], w1 = wr[1], w2 = wr[2];
      float4 v;
      v = *(const float4*)&buf[kk * 512 + ln * 8];
      FMAS12(A)
      v = *(const float4*)&buf[kk * 512 + ln * 8 + 4];
      FMAS12(B)
    }
    __syncthreads();
  }
  float* op = Out + blockIdx.y * outStride + n0;
  ST12(A, 0) ST12(B, 4)
}

// ---------------- fused W+H (I)DCT: wave-uniform basis via SGPR --------------
__global__ __launch_bounds__(256) void wh_k(const float* __restrict__ in,
    float* __restrict__ out, const float* __restrict__ basis) {
  __shared__ float Xs[64 * 65];
  int tid = threadIdx.x;
  int lane = tid & 63;
  int g0 = __builtin_amdgcn_readfirstlane((tid >> 6) * 16);  // 16-col group
  const float* ip = in + (size_t)blockIdx.x * HW;
  float* op = out + (size_t)blockIdx.x * HW;

  for (int i = tid; i < 1024; i += 256) {   // stage full 64x64 plane
    int h = i >> 4, w0x = (i & 15) * 4;
    float4 v = *(const float4*)(ip + h * 64 + w0x);
    float* d = &Xs[h * 65 + w0x];
    d[0] = v.x; d[1] = v.y; d[2] = v.z; d[3] = v.w;
  }
  __syncthreads();

  float accp[16];
#pragma unroll
  for (int j = 0; j < 16; ++j) accp[j] = 0.f;
  {
    const float* xrow = &Xs[lane * 65];
#pragma unroll 4
    for (int w = 0; w < 64; ++w) {
      float xv = xrow[w];
      const float* bw = basis + w * 64 + g0;   // uniform 64B row chunk
      float4 b0 = *(const float4*)(bw);
      float4 b1 = *(const float4*)(bw + 4);
      float4 b2 = *(const float4*)(bw + 8);
      float4 b3 = *(const float4*)(bw + 12);
      accp[0]  = fmaf(xv, b0.x, accp[0]);  accp[1]  = fmaf(xv, b0.y, accp[1]);
      accp[2]  = fmaf(xv, b0.z, accp[2]);  accp[3]  = fmaf(xv, b0.w, accp[3]);
      accp[4]  = fmaf(xv, b1.x, accp[4]);  accp[5]  = fmaf(xv, b1.y, accp[5]);
      accp[6]  = fmaf(xv, b1.z, accp[6]);  accp[7]  = fmaf(xv, b1.w, accp[7]);
      accp[8]  = fmaf(xv, b2.x, accp[8]);  accp[9]  = fmaf(xv, b2.y, accp[9]);
      accp[10] = fmaf(xv, b2.z, accp[10]); accp[11] = fmaf(xv, b2.w, accp[11]);
      accp[12] = fmaf(xv, b3.x, accp[12]); accp[13] = fmaf(xv, b3.y, accp[13]);
      accp[14] = fmaf(xv, b3.z, accp[14]); accp[15] = fmaf(xv, b3.w, accp[15]);
    }
  }
  __syncthreads();                       // all reads of Xs done
  {                                      // in-place: Xs[h][n] = Y[h][n]
    float* trow = &Xs[lane * 65 + g0];
#pragma unroll
    for (int j = 0; j < 16; ++j) trow[j] = accp[j];
  }
  __syncthreads();

  float acc2[16];
#pragma unroll
  for (int j = 0; j < 16; ++j) acc2[j] = 0.f;
#pragma unroll 4
  for (int h = 0; h < 64; ++h) {
    float tv = Xs[h * 65 + lane];
    const float* bw = basis + h * 64 + g0;     // uniform
    float4 b0 = *(const float4*)(bw);
    float4 b1 = *(const float4*)(bw + 4);
    float4 b2 = *(const float4*)(bw + 8);
    float4 b3 = *(const float4*)(bw + 12);
    acc2[0]  = fmaf(tv, b0.x, acc2[0]);  acc2[1]  = fmaf(tv, b0.y, acc2[1]);
    acc2[2]  = fmaf(tv, b0.z, acc2[2]);  acc2[3]  = fmaf(tv, b0.w, acc2[3]);
    acc2[4]  = fmaf(tv, b1.x, acc2[4]);  acc2[5]  = fmaf(tv, b1.y, acc2[5]);
    acc2[6]  = fmaf(tv, b1.z, acc2[6]);  acc2[7]  = fmaf(tv, b1.w, acc2[7]);
    acc2[8]  = fmaf(tv, b2.x, acc2[8]);  acc2[9]  = fmaf(tv, b2.y, acc2[9]);
    acc2[10] = fmaf(tv, b2.z, acc2[10]); acc2[11] = fmaf(tv, b2.w, acc2[11]);
    acc2[12] = fmaf(tv, b3.x, acc2[12]); acc2[13] = fmaf(tv, b3.y, acc2[13]);
    acc2[14] = fmaf(tv, b3.z, acc2[14]); acc2[15] = fmaf(tv, b3.w, acc2[15]);
  }
#pragma unroll
  for (int j = 0; j < 16; ++j)
    op[(g0 + j) * 64 + lane] = acc2[j];
}

// ---------------- fused T-DCT + spectral multiply + T-IDCT -------------------
__global__ __launch_bounds__(256) void tspec_k(const float* __restrict__ U0,
    const float* __restrict__ V0, const float* __restrict__ A,
    const float* __restrict__ Bc, const float* __restrict__ b16,
    float* __restrict__ out) {
  __shared__ float bs[256];
  int tid = threadIdx.x;
  bs[tid] = b16[tid];
  __syncthreads();
  int hw = blockIdx.x * 256 + tid;
  int c = blockIdx.y, b = blockIdx.z;
  size_t base = ((size_t)(b * C96 + c) * 16) * HW + hw;
  int cbase = c * THW + hw;
  float ua[16], va[16];
  {
    float u[16];
#pragma unroll
    for (int t = 0; t < 16; ++t) u[t] = U0[base + t * HW];
#pragma unroll
    for (int n = 0; n < 16; ++n) {
      float s = 0.0f;
#pragma unroll
      for (int t = 0; t < 16; ++t) s = fmaf(bs[n * 16 + t], u[t], s);
      ua[n] = s;
    }
  }
  {
    float v[16];
#pragma unroll
    for (int t = 0; t < 16; ++t) v[t] = V0[base + t * HW];
#pragma unroll
    for (int n = 0; n < 16; ++n) {
      float s = 0.0f;
#pragma unroll
      for (int t = 0; t < 16; ++t) s = fmaf(bs[n * 16 + t], v[t], s);
      va[n] = s;
    }
  }
  float so[16];
#pragma unroll 4
  for (int n = 0; n < 16; ++n)
    so[n] = A[cbase + n * HW] * ua[n] + Bc[cbase + n * HW] * va[n];
#pragma unroll
  for (int t = 0; t < 16; ++t) {
    float s = 0.0f;
#pragma unroll
    for (int n = 0; n < 16; ++n) s = fmaf(so[n], bs[n * 16 + t], s);
    out[base + t * HW] = s;
  }
}

extern "C" void kernel_launch(void* const* d_in, const int* in_sizes, int n_in,
                              void* d_out, int out_size, void* d_ws, size_t ws_size,
                              hipStream_t stream) {
  const float* x    = (const float*)d_in[0];
  const float* fe   = (const float*)d_in[1];
  const float* dww  = (const float*)d_in[2];
  const float* dwb  = (const float*)d_in[3];
  const float* linW = (const float*)d_in[4];
  const float* linB = (const float*)d_in[5];
  const float* v0W  = (const float*)d_in[6];
  const float* v0B  = (const float*)d_in[7];
  const float* tokW = (const float*)d_in[8];
  const float* tokB = (const float*)d_in[9];
  const float* cS   = (const float*)d_in[10];
  const float* aS   = (const float*)d_in[11];
  const float* lnG  = (const float*)d_in[12];
  const float* lnBp = (const float*)d_in[13];
  const float* outW = (const float*)d_in[14];
  const float* outB = (const float*)d_in[15];
  float* out = (float*)d_out;

  float* w = (float*)d_ws;
  const size_t TEN = (size_t)2 * C96 * THW;
  const size_t BST = (size_t)C96 * THW;
  float* b64    = w;                 // 4096
  float* b64T   = w + 4096;          // 4096
  float* b16    = w + 8192;          // 256
  float* buf_y  = w + 16384;
  float* buf_xg = buf_y + TEN;
  float* buf_z  = buf_xg + TEN;
  float* buf_v0 = buf_z + TEN;
  float* bufA   = buf_v0 + TEN;
  float* bufB   = bufA + BST;
  size_t need = (size_t)(16384 + 4 * TEN + 2 * BST) * sizeof(float);
  if (ws_size < need) return;

  hipLaunchKernelGGL(init_basis_k, dim3(1), dim3(256), 0, stream, b64, b64T, b16);
  hipLaunchKernelGGL(dwconv_k, dim3(192, 4, 2), dim3(256), 0, stream, x, dww, dwb, buf_y);
  hipLaunchKernelGGL(gemm96x8_k, dim3(128, 2), dim3(512), 0, stream,
                     buf_y, linW, linB, buf_xg, THW, BST, BST);
  hipLaunchKernelGGL(gemm96x8_k, dim3(128, 2), dim3(512), 0, stream,
                     buf_y, linW + 9216, linB + 96, buf_z, THW, BST, BST);
  hipLaunchKernelGGL(feT_k, dim3(1024), dim3(256), 0, stream, fe, buf_v0);
  hipLaunchKernelGGL((gemm96_k<1>), dim3(256, 1), dim3(512), 0, stream,
                     buf_v0, tokW, tokB, bufA, bufB, (const float*)nullptr,
                     (const float*)nullptr, (const float*)nullptr,
                     cS, aS, THW, (size_t)0, (size_t)0);
  hipLaunchKernelGGL(gemm96x8_k, dim3(128, 2), dim3(512), 0, stream,
                     buf_xg, v0W, v0B, buf_v0, THW, BST, BST);
  hipLaunchKernelGGL(wh_k, dim3(3072), dim3(256), 0, stream, buf_xg, buf_y, b64T);
  hipLaunchKernelGGL(wh_k, dim3(3072), dim3(256), 0, stream, buf_v0, buf_xg, b64T);
  hipLaunchKernelGGL(tspec_k, dim3(16, 96, 2), dim3(256), 0, stream, buf_y, buf_xg, bufA, bufB, b16, buf_v0);
  hipLaunchKernelGGL(wh_k, dim3(3072), dim3(256), 0, stream, buf_v0, buf_y, b64);
  hipLaunchKernelGGL((gemm96_k<2>), dim3(256, 2), dim3(512), 0, stream,
                     buf_y, outW, outB, out, (float*)nullptr, buf_z,
                     lnG, lnBp, (const float*)nullptr, (const float*)nullptr, THW, BST, BST);
}

// Round 9
// 531.239 us; speedup vs baseline: 1.1254x; 1.1005x over previous
//
#include <hip/hip_runtime.h>
#include <math.h>

#define THW 65536
#define HW  4096
#define C96 96
#ifndef M_PI
#define M_PI 3.14159265358979323846
#endif

// ---------------- basis init (once per launch; ws is re-poisoned each call) --
__global__ __launch_bounds__(256) void init_basis_k(float* __restrict__ b64,
                                                    float* __restrict__ b64T,
                                                    float* __restrict__ b16) {
  int tid = threadIdx.x;
  for (int i = tid; i < 4096; i += 256) {
    int n = i >> 6, x = i & 63;
    double s = sqrt(2.0 / 64.0) * (n == 0 ? sqrt(0.5) : 1.0);
    float v = (float)(cos((double)n * ((double)x + 0.5) * M_PI / 64.0) * s);
    b64[i] = v;
    b64T[x * 64 + n] = v;
  }
  {
    int n = tid >> 4, x = tid & 15;
    double s = sqrt(2.0 / 16.0) * (n == 0 ? sqrt(0.5) : 1.0);
    b16[tid & 255] = (float)(cos((double)n * ((double)x + 0.5) * M_PI / 16.0) * s);
  }
}

// ---------------- depthwise 3x3x3 conv: lane-per-w, shuffle halo, LDS-free ---
struct R3 { float a, b, c; };  // planes t-1, t, t+1 at one (h,w=lane)

#define LOADR(dst, row) { int rr_ = (row); int o_ = rr_ * 64 + lane; \
    dst.a = pmv[o_]; dst.b = pcv[o_]; dst.c = ppv[o_]; }

#define OUTROW(A, B, Cc, row) { \
    float P0, P1, P2; \
    P0 = w27[0]  * A.a;          P1 = w27[1]  * A.a;          P2 = w27[2]  * A.a; \
    P0 = fmaf(w27[3],  B.a, P0); P1 = fmaf(w27[4],  B.a, P1); P2 = fmaf(w27[5],  B.a, P2); \
    P0 = fmaf(w27[6],  Cc.a, P0); P1 = fmaf(w27[7],  Cc.a, P1); P2 = fmaf(w27[8],  Cc.a, P2); \
    P0 = fmaf(w27[9],  A.b, P0); P1 = fmaf(w27[10], A.b, P1); P2 = fmaf(w27[11], A.b, P2); \
    P0 = fmaf(w27[12], B.b, P0); P1 = fmaf(w27[13], B.b, P1); P2 = fmaf(w27[14], B.b, P2); \
    P0 = fmaf(w27[15], Cc.b, P0); P1 = fmaf(w27[16], Cc.b, P1); P2 = fmaf(w27[17], Cc.b, P2); \
    P0 = fmaf(w27[18], A.c, P0); P1 = fmaf(w27[19], A.c, P1); P2 = fmaf(w27[20], A.c, P2); \
    P0 = fmaf(w27[21], B.c, P0); P1 = fmaf(w27[22], B.c, P1); P2 = fmaf(w27[23], B.c, P2); \
    P0 = fmaf(w27[24], Cc.c, P0); P1 = fmaf(w27[25], Cc.c, P1); P2 = fmaf(w27[26], Cc.c, P2); \
    float lft = __shfl_up(P0, 1);  if (lane == 0)  lft = 0.f; \
    float rgt = __shfl_down(P2, 1); if (lane == 63) rgt = 0.f; \
    yp[(row) * 64] = bv + lft + P1 + rgt; }

__global__ __launch_bounds__(256) void dwconv_k(const float* __restrict__ x,
    const float* __restrict__ wv, const float* __restrict__ bias,
    float* __restrict__ y) {
  int lane = threadIdx.x & 63;
  int wvi  = threadIdx.x >> 6;            // 0..3
  int bc   = blockIdx.x;                  // 0..191
  int t    = blockIdx.y * 4 + wvi;        // 0..15
  int h0   = blockIdx.z * 32;             // 0 or 32
  int c    = bc % C96;

  const float* pcv = x + (size_t)bc * THW + (size_t)t * HW;
  const float* pmv = (t > 0)  ? pcv - HW : pcv;
  const float* ppv = (t < 15) ? pcv + HW : pcv;

  float w27[27];
#pragma unroll
  for (int i = 0; i < 27; ++i) w27[i] = wv[c * 27 + i];
  if (t == 0) {
#pragma unroll
    for (int i = 0; i < 9; ++i) w27[i] = 0.f;
  }
  if (t == 15) {
#pragma unroll
    for (int i = 0; i < 9; ++i) w27[18 + i] = 0.f;
  }
  float bv = bias[c];
  float* yp = y + (size_t)bc * THW + (size_t)t * HW + lane;

  R3 s0, s1, s2, s3, n0, n1;
  if (h0 > 0) { LOADR(s0, h0 - 1) } else { s0.a = s0.b = s0.c = 0.f; }
  LOADR(s1, h0)
  LOADR(s2, h0 + 1)
  LOADR(s3, h0 + 2)
#pragma unroll
  for (int p = 0; p < 14; ++p) {
    int h = h0 + 2 * p;
    LOADR(n0, h + 3)
    LOADR(n1, h + 4)
    OUTROW(s0, s1, s2, h)
    OUTROW(s1, s2, s3, h + 1)
    s0 = s2; s1 = s3; s2 = n0; s3 = n1;
  }
  {
    int h = h0 + 28;
    LOADR(n0, h + 3)
    if (h0 == 0) { LOADR(n1, h + 4) }
    else { n1.a = n1.b = n1.c = 0.f; }
    OUTROW(s0, s1, s2, h)
    OUTROW(s1, s2, s3, h + 1)
    s0 = s2; s1 = s3; s2 = n0; s3 = n1;
  }
  {
    int h = h0 + 30;
    OUTROW(s0, s1, s2, h)
    OUTROW(s1, s2, s3, h + 1)
  }
}
#undef LOADR
#undef OUTROW

// ---------------- fe transpose: [THW][96] -> [96][THW] -----------------------
__global__ __launch_bounds__(256) void feT_k(const float* __restrict__ fe,
                                             float* __restrict__ feT) {
  __shared__ float t[96 * 65];
  int tid = threadIdx.x;
  int tok0 = blockIdx.x * 64;
  const float* p = fe + (size_t)tok0 * 96;
  for (int i = tid; i < 6144; i += 256) {
    int tok = i / 96;
    int ch = i - tok * 96;
    t[ch * 65 + tok] = p[i];
  }
  __syncthreads();
  for (int i = tid; i < 6144; i += 256) {
    int ch = i >> 6, tok = i & 63;
    feT[(size_t)ch * THW + tok0 + tok] = t[ch * 65 + tok];
  }
}

// ---------------- LDS-staged 96xN GEMM family, 512 threads (R1-verified) -----
// 8 waves x 12 outputs each -> acc[12] = 48 VGPR (cannot spill).
#define FMA4(A, WV) \
  A.x = fmaf(WV, v.x, A.x); A.y = fmaf(WV, v.y, A.y); \
  A.z = fmaf(WV, v.z, A.z); A.w = fmaf(WV, v.w, A.w);

#define WPAD 104
#define BK32 32

template <int EPI>
__global__ __launch_bounds__(512) void gemm96_k(
    const float* __restrict__ In, const float* __restrict__ W,
    const float* __restrict__ bias, float* __restrict__ Out,
    float* __restrict__ Out2, const float* __restrict__ zg,
    const float* __restrict__ lnG, const float* __restrict__ lnB,
    const float* __restrict__ scal_c, const float* __restrict__ scal_a,
    int N, size_t inStride, size_t outStride) {
  __shared__ float Wt[96 * WPAD];      // [k][co], padded (39 KB)
  __shared__ float buf[BK32 * 256];    // 32 KB
  int tid = threadIdx.x;
  int wvi = tid >> 6, ln = tid & 63;   // 8 waves
  for (int i = tid; i < 2304; i += 512) {
    int k4 = i / 96, co = i - k4 * 96;
    float4 w4 = *(const float4*)(W + co * 96 + k4 * 4);
    int k = k4 * 4;
    Wt[(k + 0) * WPAD + co] = w4.x;
    Wt[(k + 1) * WPAD + co] = w4.y;
    Wt[(k + 2) * WPAD + co] = w4.z;
    Wt[(k + 3) * WPAD + co] = w4.w;
  }
  int n0 = blockIdx.x * 256 + ln * 4;
  int co0 = wvi * 12;
  const float* ipb = In + blockIdx.y * inStride + blockIdx.x * 256 + ln * 4;
  const float* zpb = (EPI == 2) ? (zg + blockIdx.y * inStride + blockIdx.x * 256 + ln * 4)
                                : nullptr;

  float4 mu4, rs4;
  if (EPI == 2) {   // per-token LN stats for this lane's 4 tokens
    float4 sum = make_float4(0.f, 0.f, 0.f, 0.f);
    float4 sq  = make_float4(0.f, 0.f, 0.f, 0.f);
#pragma unroll 8
    for (int ci = 0; ci < 96; ++ci) {
      float4 t = *(const float4*)(ipb + (size_t)ci * N);
      sum.x += t.x; sum.y += t.y; sum.z += t.z; sum.w += t.w;
      sq.x = fmaf(t.x, t.x, sq.x); sq.y = fmaf(t.y, t.y, sq.y);
      sq.z = fmaf(t.z, t.z, sq.z); sq.w = fmaf(t.w, t.w, sq.w);
    }
    const float r96 = 1.0f / 96.0f;
    mu4.x = sum.x * r96; mu4.y = sum.y * r96; mu4.z = sum.z * r96; mu4.w = sum.w * r96;
    rs4.x = rsqrtf(fmaxf(sq.x * r96 - mu4.x * mu4.x, 0.f) + 1e-5f);
    rs4.y = rsqrtf(fmaxf(sq.y * r96 - mu4.y * mu4.y, 0.f) + 1e-5f);
    rs4.z = rsqrtf(fmaxf(sq.z * r96 - mu4.z * mu4.z, 0.f) + 1e-5f);
    rs4.w = rsqrtf(fmaxf(sq.w * r96 - mu4.w * mu4.w, 0.f) + 1e-5f);
  }

  float4 acc[12];
#pragma unroll
  for (int j = 0; j < 12; ++j) {
    float bj = bias[co0 + j];
    acc[j] = make_float4(bj, bj, bj, bj);
  }

#pragma unroll 1
  for (int kb = 0; kb < 3; ++kb) {
#pragma unroll
    for (int i = 0; i < 4; ++i) {           // 32 rows by 8 waves
      int r = i * 8 + wvi;
      int k = kb * BK32 + r;
      float4 v4 = *(const float4*)(ipb + (size_t)k * N);
      if (EPI == 2) {
        float4 zz = *(const float4*)(zpb + (size_t)k * N);
        float lgk = lnG[k], lbk = lnB[k];
        float gx = zz.x * __builtin_amdgcn_rcpf(1.0f + __expf(-zz.x));
        float gy = zz.y * __builtin_amdgcn_rcpf(1.0f + __expf(-zz.y));
        float gz = zz.z * __builtin_amdgcn_rcpf(1.0f + __expf(-zz.z));
        float gw = zz.w * __builtin_amdgcn_rcpf(1.0f + __expf(-zz.w));
        v4.x = fmaf((v4.x - mu4.x) * rs4.x, lgk, lbk) * gx;
        v4.y = fmaf((v4.y - mu4.y) * rs4.y, lgk, lbk) * gy;
        v4.z = fmaf((v4.z - mu4.z) * rs4.z, lgk, lbk) * gz;
        v4.w = fmaf((v4.w - mu4.w) * rs4.w, lgk, lbk) * gw;
      }
      *(float4*)&buf[r * 256 + ln * 4] = v4;
    }
    __syncthreads();
#pragma unroll 8
    for (int kk = 0; kk < BK32; ++kk) {
      int k = kb * BK32 + kk;
      float4 v = *(const float4*)&buf[kk * 256 + ln * 4];
      const float4* wr = (const float4*)&Wt[k * WPAD + co0];
#pragma unroll
      for (int j = 0; j < 3; ++j) {
        float4 wvv = wr[j];
        FMA4(acc[4 * j + 0], wvv.x);
        FMA4(acc[4 * j + 1], wvv.y);
        FMA4(acc[4 * j + 2], wvv.z);
        FMA4(acc[4 * j + 3], wvv.w);
      }
    }
    __syncthreads();
  }

  if (EPI == 1) {
    float cv = scal_c[0], al = scal_a[0];
    float rc = 1.0f / (cv + 1e-8f);
#define TAUMAP(T, AA, BB) { \
    float tau = 0.5f * (T) * (1.0f + erff((T) * 0.70710678118654752f)); \
    float ct = cv * tau; \
    float damp = __expf(-0.5f * al * tau); \
    float sc = __sinf(ct), cc = __cosf(ct); \
    AA = damp * (cc + sc * al * 0.5f * rc); BB = damp * sc * rc; }
#pragma unroll 2
    for (int j = 0; j < 12; ++j) {
      float4 a4, b4;
      TAUMAP(acc[j].x, a4.x, b4.x);
      TAUMAP(acc[j].y, a4.y, b4.y);
      TAUMAP(acc[j].z, a4.z, b4.z);
      TAUMAP(acc[j].w, a4.w, b4.w);
      *(float4*)(Out  + (size_t)(co0 + j) * N + n0) = a4;
      *(float4*)(Out2 + (size_t)(co0 + j) * N + n0) = b4;
    }
#undef TAUMAP
  } else {
    float* op = Out + blockIdx.y * outStride + n0;
#pragma unroll
    for (int j = 0; j < 12; ++j)
      *(float4*)(op + (size_t)(co0 + j) * N) = acc[j];
  }
}

// ---------------- dual-output lin GEMM: y -> (xg, z) in ONE pass -------------
// Both matrices share input y: token staging, y fetch, and barriers paid once.
// 24 NAMED float4 accumulators (no alloca -> cannot be demoted to scratch).
// Wt pitch 96: weight reads are wave-broadcast (same addr) -> conflict-free.
#define INIT1B(p, j, bp) float4 p##j; { float bj_ = bp[co0 + j]; \
    p##j = make_float4(bj_, bj_, bj_, bj_); }
#define INIT12B(p, bp) INIT1B(p,0,bp) INIT1B(p,1,bp) INIT1B(p,2,bp) \
    INIT1B(p,3,bp) INIT1B(p,4,bp) INIT1B(p,5,bp) INIT1B(p,6,bp) \
    INIT1B(p,7,bp) INIT1B(p,8,bp) INIT1B(p,9,bp) INIT1B(p,10,bp) INIT1B(p,11,bp)
#define FMAS12(p) \
  FMA4(p##0, w0.x); FMA4(p##1, w0.y); FMA4(p##2,  w0.z); FMA4(p##3,  w0.w); \
  FMA4(p##4, w1.x); FMA4(p##5, w1.y); FMA4(p##6,  w1.z); FMA4(p##7,  w1.w); \
  FMA4(p##8, w2.x); FMA4(p##9, w2.y); FMA4(p##10, w2.z); FMA4(p##11, w2.w);
#define ST1P(p, j, op) *(float4*)((op) + (size_t)(co0 + j) * N + n0) = p##j;
#define ST12P(p, op) ST1P(p,0,op) ST1P(p,1,op) ST1P(p,2,op) ST1P(p,3,op) \
    ST1P(p,4,op) ST1P(p,5,op) ST1P(p,6,op) ST1P(p,7,op) ST1P(p,8,op) \
    ST1P(p,9,op) ST1P(p,10,op) ST1P(p,11,op)

__global__ __launch_bounds__(512) void dual_lin_k(
    const float* __restrict__ In, const float* __restrict__ WA,
    const float* __restrict__ WB, const float* __restrict__ biasA,
    const float* __restrict__ biasB, float* __restrict__ OutA,
    float* __restrict__ OutB, int N, size_t inStride, size_t outStride) {
  __shared__ float WtA[96 * 96];       // 36 KB
  __shared__ float WtB[96 * 96];       // 36 KB
  __shared__ float buf[BK32 * 256];    // 32 KB  -> 104 KB total, 1 block/CU
  int tid = threadIdx.x;
  int wvi = tid >> 6, ln = tid & 63;   // 8 waves
  for (int i = tid; i < 2304; i += 512) {
    int k4 = i / 96, co = i - k4 * 96;
    int k = k4 * 4;
    float4 a4 = *(const float4*)(WA + co * 96 + k4 * 4);
    WtA[(k + 0) * 96 + co] = a4.x;
    WtA[(k + 1) * 96 + co] = a4.y;
    WtA[(k + 2) * 96 + co] = a4.z;
    WtA[(k + 3) * 96 + co] = a4.w;
    float4 b4 = *(const float4*)(WB + co * 96 + k4 * 4);
    WtB[(k + 0) * 96 + co] = b4.x;
    WtB[(k + 1) * 96 + co] = b4.y;
    WtB[(k + 2) * 96 + co] = b4.z;
    WtB[(k + 3) * 96 + co] = b4.w;
  }
  int n0 = blockIdx.x * 256 + ln * 4;
  int co0 = wvi * 12;
  const float* ipb = In + blockIdx.y * inStride + n0;

  INIT12B(A, biasA) INIT12B(B, biasB)

#pragma unroll 1
  for (int kb = 0; kb < 3; ++kb) {
#pragma unroll
    for (int i = 0; i < 4; ++i) {           // 32 rows by 8 waves
      int r = i * 8 + wvi;
      int k = kb * BK32 + r;
      *(float4*)&buf[r * 256 + ln * 4] = *(const float4*)(ipb + (size_t)k * N);
    }
    __syncthreads();
#pragma unroll 4
    for (int kk = 0; kk < BK32; ++kk) {
      int k = kb * BK32 + kk;
      float4 v = *(const float4*)&buf[kk * 256 + ln * 4];
      {
        const float4* wr = (const float4*)&WtA[k * 96 + co0];
        float4 w0 = wr[0], w1 = wr[1], w2 = wr[2];
        FMAS12(A)
      }
      {
        const float4* wr = (const float4*)&WtB[k * 96 + co0];
        float4 w0 = wr[0], w1 = wr[1], w2 = wr[2];
        FMAS12(B)
      }
    }
    __syncthreads();
  }

  float* opA = OutA + blockIdx.y * outStride;
  float* opB = OutB + blockIdx.y * outStride;
  ST12P(A, opA) ST12P(B, opB)
}

// ---------------- fused W+H (I)DCT: wave-uniform basis via SGPR --------------
__global__ __launch_bounds__(256) void wh_k(const float* __restrict__ in,
    float* __restrict__ out, const float* __restrict__ basis) {
  __shared__ float Xs[64 * 65];
  int tid = threadIdx.x;
  int lane = tid & 63;
  int g0 = __builtin_amdgcn_readfirstlane((tid >> 6) * 16);  // 16-col group
  const float* ip = in + (size_t)blockIdx.x * HW;
  float* op = out + (size_t)blockIdx.x * HW;

  for (int i = tid; i < 1024; i += 256) {   // stage full 64x64 plane
    int h = i >> 4, w0x = (i & 15) * 4;
    float4 v = *(const float4*)(ip + h * 64 + w0x);
    float* d = &Xs[h * 65 + w0x];
    d[0] = v.x; d[1] = v.y; d[2] = v.z; d[3] = v.w;
  }
  __syncthreads();

  float accp[16];
#pragma unroll
  for (int j = 0; j < 16; ++j) accp[j] = 0.f;
  {
    const float* xrow = &Xs[lane * 65];
#pragma unroll 4
    for (int w = 0; w < 64; ++w) {
      float xv = xrow[w];
      const float* bw = basis + w * 64 + g0;   // uniform 64B row chunk
      float4 b0 = *(const float4*)(bw);
      float4 b1 = *(const float4*)(bw + 4);
      float4 b2 = *(const float4*)(bw + 8);
      float4 b3 = *(const float4*)(bw + 12);
      accp[0]  = fmaf(xv, b0.x, accp[0]);  accp[1]  = fmaf(xv, b0.y, accp[1]);
      accp[2]  = fmaf(xv, b0.z, accp[2]);  accp[3]  = fmaf(xv, b0.w, accp[3]);
      accp[4]  = fmaf(xv, b1.x, accp[4]);  accp[5]  = fmaf(xv, b1.y, accp[5]);
      accp[6]  = fmaf(xv, b1.z, accp[6]);  accp[7]  = fmaf(xv, b1.w, accp[7]);
      accp[8]  = fmaf(xv, b2.x, accp[8]);  accp[9]  = fmaf(xv, b2.y, accp[9]);
      accp[10] = fmaf(xv, b2.z, accp[10]); accp[11] = fmaf(xv, b2.w, accp[11]);
      accp[12] = fmaf(xv, b3.x, accp[12]); accp[13] = fmaf(xv, b3.y, accp[13]);
      accp[14] = fmaf(xv, b3.z, accp[14]); accp[15] = fmaf(xv, b3.w, accp[15]);
    }
  }
  __syncthreads();                       // all reads of Xs done
  {                                      // in-place: Xs[h][n] = Y[h][n]
    float* trow = &Xs[lane * 65 + g0];
#pragma unroll
    for (int j = 0; j < 16; ++j) trow[j] = accp[j];
  }
  __syncthreads();

  float acc2[16];
#pragma unroll
  for (int j = 0; j < 16; ++j) acc2[j] = 0.f;
#pragma unroll 4
  for (int h = 0; h < 64; ++h) {
    float tv = Xs[h * 65 + lane];
    const float* bw = basis + h * 64 + g0;     // uniform
    float4 b0 = *(const float4*)(bw);
    float4 b1 = *(const float4*)(bw + 4);
    float4 b2 = *(const float4*)(bw + 8);
    float4 b3 = *(const float4*)(bw + 12);
    acc2[0]  = fmaf(tv, b0.x, acc2[0]);  acc2[1]  = fmaf(tv, b0.y, acc2[1]);
    acc2[2]  = fmaf(tv, b0.z, acc2[2]);  acc2[3]  = fmaf(tv, b0.w, acc2[3]);
    acc2[4]  = fmaf(tv, b1.x, acc2[4]);  acc2[5]  = fmaf(tv, b1.y, acc2[5]);
    acc2[6]  = fmaf(tv, b1.z, acc2[6]);  acc2[7]  = fmaf(tv, b1.w, acc2[7]);
    acc2[8]  = fmaf(tv, b2.x, acc2[8]);  acc2[9]  = fmaf(tv, b2.y, acc2[9]);
    acc2[10] = fmaf(tv, b2.z, acc2[10]); acc2[11] = fmaf(tv, b2.w, acc2[11]);
    acc2[12] = fmaf(tv, b3.x, acc2[12]); acc2[13] = fmaf(tv, b3.y, acc2[13]);
    acc2[14] = fmaf(tv, b3.z, acc2[14]); acc2[15] = fmaf(tv, b3.w, acc2[15]);
  }
#pragma unroll
  for (int j = 0; j < 16; ++j)
    op[(g0 + j) * 64 + lane] = acc2[j];
}

// ---------------- fused T-DCT + spectral multiply + T-IDCT -------------------
__global__ __launch_bounds__(256) void tspec_k(const float* __restrict__ U0,
    const float* __restrict__ V0, const float* __restrict__ A,
    const float* __restrict__ Bc, const float* __restrict__ b16,
    float* __restrict__ out) {
  __shared__ float bs[256];
  int tid = threadIdx.x;
  bs[tid] = b16[tid];
  __syncthreads();
  int hw = blockIdx.x * 256 + tid;
  int c = blockIdx.y, b = blockIdx.z;
  size_t base = ((size_t)(b * C96 + c) * 16) * HW + hw;
  int cbase = c * THW + hw;
  float ua[16], va[16];
  {
    float u[16];
#pragma unroll
    for (int t = 0; t < 16; ++t) u[t] = U0[base + t * HW];
#pragma unroll
    for (int n = 0; n < 16; ++n) {
      float s = 0.0f;
#pragma unroll
      for (int t = 0; t < 16; ++t) s = fmaf(bs[n * 16 + t], u[t], s);
      ua[n] = s;
    }
  }
  {
    float v[16];
#pragma unroll
    for (int t = 0; t < 16; ++t) v[t] = V0[base + t * HW];
#pragma unroll
    for (int n = 0; n < 16; ++n) {
      float s = 0.0f;
#pragma unroll
      for (int t = 0; t < 16; ++t) s = fmaf(bs[n * 16 + t], v[t], s);
      va[n] = s;
    }
  }
  float so[16];
#pragma unroll 4
  for (int n = 0; n < 16; ++n)
    so[n] = A[cbase + n * HW] * ua[n] + Bc[cbase + n * HW] * va[n];
#pragma unroll
  for (int t = 0; t < 16; ++t) {
    float s = 0.0f;
#pragma unroll
    for (int n = 0; n < 16; ++n) s = fmaf(so[n], bs[n * 16 + t], s);
    out[base + t * HW] = s;
  }
}

extern "C" void kernel_launch(void* const* d_in, const int* in_sizes, int n_in,
                              void* d_out, int out_size, void* d_ws, size_t ws_size,
                              hipStream_t stream) {
  const float* x    = (const float*)d_in[0];
  const float* fe   = (const float*)d_in[1];
  const float* dww  = (const float*)d_in[2];
  const float* dwb  = (const float*)d_in[3];
  const float* linW = (const float*)d_in[4];
  const float* linB = (const float*)d_in[5];
  const float* v0W  = (const float*)d_in[6];
  const float* v0B  = (const float*)d_in[7];
  const float* tokW = (const float*)d_in[8];
  const float* tokB = (const float*)d_in[9];
  const float* cS   = (const float*)d_in[10];
  const float* aS   = (const float*)d_in[11];
  const float* lnG  = (const float*)d_in[12];
  const float* lnBp = (const float*)d_in[13];
  const float* outW = (const float*)d_in[14];
  const float* outB = (const float*)d_in[15];
  float* out = (float*)d_out;

  float* w = (float*)d_ws;
  const size_t TEN = (size_t)2 * C96 * THW;
  const size_t BST = (size_t)C96 * THW;
  float* b64    = w;                 // 4096
  float* b64T   = w + 4096;          // 4096
  float* b16    = w + 8192;          // 256
  float* buf_y  = w + 16384;
  float* buf_xg = buf_y + TEN;
  float* buf_z  = buf_xg + TEN;
  float* buf_v0 = buf_z + TEN;
  float* bufA   = buf_v0 + TEN;
  float* bufB   = bufA + BST;
  size_t need = (size_t)(16384 + 4 * TEN + 2 * BST) * sizeof(float);
  if (ws_size < need) return;

  hipLaunchKernelGGL(init_basis_k, dim3(1), dim3(256), 0, stream, b64, b64T, b16);
  hipLaunchKernelGGL(dwconv_k, dim3(192, 4, 2), dim3(256), 0, stream, x, dww, dwb, buf_y);
  hipLaunchKernelGGL(dual_lin_k, dim3(256, 2), dim3(512), 0, stream,
                     buf_y, linW, linW + 9216, linB, linB + 96,
                     buf_xg, buf_z, THW, BST, BST);
  hipLaunchKernelGGL(feT_k, dim3(1024), dim3(256), 0, stream, fe, buf_v0);
  hipLaunchKernelGGL((gemm96_k<1>), dim3(256, 1), dim3(512), 0, stream,
                     buf_v0, tokW, tokB, bufA, bufB, (const float*)nullptr,
                     (const float*)nullptr, (const float*)nullptr,
                     cS, aS, THW, (size_t)0, (size_t)0);
  hipLaunchKernelGGL((gemm96_k<0>), dim3(256, 2), dim3(512), 0, stream,
                     buf_xg, v0W, v0B, buf_v0, (float*)nullptr, (const float*)nullptr,
                     (const float*)nullptr, (const float*)nullptr,
                     (const float*)nullptr, (const float*)nullptr, THW, BST, BST);
  hipLaunchKernelGGL(wh_k, dim3(3072), dim3(256), 0, stream, buf_xg, buf_y, b64T);
  hipLaunchKernelGGL(wh_k, dim3(3072), dim3(256), 0, stream, buf_v0, buf_xg, b64T);
  hipLaunchKernelGGL(tspec_k, dim3(16, 96, 2), dim3(256), 0, stream, buf_y, buf_xg, bufA, bufB, b16, buf_v0);
  hipLaunchKernelGGL(wh_k, dim3(3072), dim3(256), 0, stream, buf_v0, buf_y, b64);
  hipLaunchKernelGGL((gemm96_k<2>), dim3(256, 2), dim3(512), 0, stream,
                     buf_y, outW, outB, out, (float*)nullptr, buf_z,
                     lnG, lnBp, (const float*)nullptr, (const float*)nullptr, THW, BST, BST);
}